// Round 10
// baseline (433.759 us; speedup 1.0000x reference)
//
#include <hip/hip_runtime.h>
#include <hip/hip_bf16.h>
#include <stdint.h>

// Problem constants
#define NND   100000      // nodes
#define NED   400000      // edges
#define KD    512         // DIN
#define ND    512         // DOUT
#define PDROP 0.1f
#define INV_KEEP (1.0f/0.9f)

#define BM   32           // rows per block (full N=512 width -> A read once from HBM)
#define NT   16           // K-steps of 32
#define NBLK 3128         // 100096/32

typedef __attribute__((ext_vector_type(4))) float f32x4;
typedef __attribute__((ext_vector_type(8))) short short8;
typedef __attribute__((ext_vector_type(8))) unsigned short ushort8;

// ---- ws layout (bytes) ----
#define WT_OFF   102498304    // wts bf16, fragment-ordered W^T, 512 KB
#define HP_OFF   103022592    // hp_bf16 [MPAD][512]
#define DEG_OFF  205520896    // deg_u32 [NND]
#define DINV_OFF 205920896    // dinv_f32[NND]
#define OFFS_OFF 206320896    // offs_u32[NND] (CSR cursor -> local ends)
#define SRCS_OFF 206720896    // srcs_i32[NED]
#define BSUM_OFF 208320896    // block sums (391 u32)

__device__ __forceinline__ unsigned short f2bf(float f) {
  unsigned int x = __float_as_uint(f);
  unsigned int r = (x + 0x7fffu + ((x >> 16) & 1u)) >> 16;
  return (unsigned short)r;
}
__device__ __forceinline__ float bf2f(unsigned short u) {
  return __uint_as_float(((unsigned int)u) << 16);
}

// ---------- prep: fragment-ordered W^T to bf16 (blocks 0..1023) + degree count ----------
// wts[idx], idx = kt*16384 + wn*4096 + n*512 + lane*8 + e
//   holds W^T[row = wn*128 + n*16 + (lane&15)][k = kt*32 + (lane>>4)*8 + e]
// so in k_fused, b[n] for (wn,kt) is one lane-coalesced dwordx4 load.
__global__ void k_prep(const float* __restrict__ W, unsigned short* __restrict__ wts,
                       const int* __restrict__ ei, unsigned int* __restrict__ deg) {
  int bb = blockIdx.x;
  if (bb < 1024) {
    int idx = bb * 256 + threadIdx.x;        // 262144 total
    int e    = idx & 7;
    int lane = (idx >> 3) & 63;
    int n    = (idx >> 9) & 7;
    int wn   = (idx >> 12) & 3;
    int kt   = idx >> 14;
    int row = wn * 128 + n * 16 + (lane & 15);
    int k   = kt * 32 + (lane >> 4) * 8 + e;
    wts[idx] = f2bf(W[(size_t)k * 512 + row]);
  } else {
    int e = (bb - 1024) * 256 + threadIdx.x;
    if (e < NED) atomicAdd(&deg[ei[NED + e]], 1u);   // col = destination
  }
}

// ---------- exclusive scan of deg -> offs (+ dinv fused) ----------
__global__ void k_scan1(const unsigned int* __restrict__ deg,
                        unsigned int* __restrict__ offs, unsigned int* __restrict__ bsum,
                        float* __restrict__ dinv) {
  __shared__ unsigned int s[256];
  int tid = threadIdx.x;
  int i = blockIdx.x * 256 + tid;
  unsigned int v = (i < NND) ? deg[i] : 0u;
  if (i < NND) dinv[i] = rsqrtf((float)(v + 1u));   // +1 self-loop
  s[tid] = v;
  __syncthreads();
  for (int d = 1; d < 256; d <<= 1) {
    unsigned int t = (tid >= d) ? s[tid - d] : 0u;
    __syncthreads();
    s[tid] += t;
    __syncthreads();
  }
  if (i < NND) offs[i] = s[tid] - v;          // block-local exclusive
  if (tid == 255) bsum[blockIdx.x] = s[255];
}
__global__ void k_scan2(unsigned int* __restrict__ bsum) {   // 391 entries
  __shared__ unsigned int s[512];
  int t = threadIdx.x;
  unsigned int v = (t < 391) ? bsum[t] : 0u;
  s[t] = v;
  __syncthreads();
  for (int d = 1; d < 512; d <<= 1) {
    unsigned int u = (t >= d) ? s[t - d] : 0u;
    __syncthreads();
    s[t] += u;
    __syncthreads();
  }
  if (t < 391) bsum[t] = s[t] - v;            // exclusive block offsets
}

// ---------- CSR fill (global pos = local cursor + bsum[dst block]) ----------
__global__ void k_fill(const int* __restrict__ ei, unsigned int* __restrict__ offs,
                       const unsigned int* __restrict__ bsum, int* __restrict__ srcs) {
  int e = blockIdx.x * 256 + threadIdx.x;
  if (e < NED) {
    int dst = ei[NED + e];
    unsigned int pos = atomicAdd(&offs[dst], 1u) + bsum[dst >> 8];
    srcs[pos] = ei[e];
  }
}

// ---------- fused dropout + bf16 MFMA GEMM, ZERO-LDS / ZERO-BARRIER ----------
// hp = dinv_row * (dropout(x) @ W).  BM=32 x BN=512, 256 thr = 4 waves (1M x 4N),
// wave tile 32x128, acc[2][8].  All operands register-direct:
//   B: 8 lane-coalesced dwordx4/step from fragment-ordered wts (L1/L2-hot).
//   A: per-lane 32B x + 32B dm for its own fragment rows (zero intra-wave
//      redundancy; x4 cross-wave re-read served by L1/L2), dropout in-reg.
// Waves fully independent -> latency hidden by ILP + 3 waves/SIMD.
__global__ void __launch_bounds__(256, 3)
k_fused(const float* __restrict__ x, const float* __restrict__ dm,
        const unsigned short* __restrict__ wts,
        const float* __restrict__ dinv,
        unsigned short* __restrict__ hp) {
  const int t = threadIdx.x, wn = t >> 6, lane = t & 63;
  const int fr = lane & 15, kg = lane >> 4;
  const int mb = blockIdx.x * BM;

  const int r0 = mb + fr, r1 = mb + 16 + fr;
  const bool ok0 = r0 < NND, ok1 = r1 < NND;
  const float* xp0 = x + (size_t)(ok0 ? r0 : 0) * KD + kg * 8;
  const float* mp0 = dm + (size_t)(ok0 ? r0 : 0) * KD + kg * 8;
  const float* xp1 = x + (size_t)(ok1 ? r1 : 0) * KD + kg * 8;
  const float* mp1 = dm + (size_t)(ok1 ? r1 : 0) * KD + kg * 8;
  const unsigned short* bp = wts + wn * 4096 + lane * 8;

  f32x4 zero = {0.f, 0.f, 0.f, 0.f};
  f32x4 acc[2][8];
  #pragma unroll
  for (int n = 0; n < 8; ++n) { acc[0][n] = zero; acc[1][n] = zero; }

  // A-reg pipeline (1 step ahead): 8 float4 held
  float4 xa0 = *(const float4*)(xp0);     float4 xb0 = *(const float4*)(xp0 + 4);
  float4 ma0 = *(const float4*)(mp0);     float4 mb0 = *(const float4*)(mp0 + 4);
  float4 xa1 = *(const float4*)(xp1);     float4 xb1 = *(const float4*)(xp1 + 4);
  float4 ma1 = *(const float4*)(mp1);     float4 mb1 = *(const float4*)(mp1 + 4);

  #pragma unroll 2
  for (int kt = 0; kt < NT; ++kt) {
    // B fragments for this step: 8 coalesced 16B loads (L1/L2)
    short8 b[8];
    #pragma unroll
    for (int n = 0; n < 8; ++n)
      b[n] = *(const short8*)(bp + kt * 16384 + n * 512);

    // afrag from held regs (dropout + cvt in-register)
    ushort8 a0, a1;
    {
      const float* xs = (const float*)&xa0; const float* ms = (const float*)&ma0;
      #pragma unroll
      for (int j = 0; j < 4; ++j) a0[j] = (ok0 && ms[j] >= PDROP) ? f2bf(xs[j] * INV_KEEP) : 0;
      xs = (const float*)&xb0; ms = (const float*)&mb0;
      #pragma unroll
      for (int j = 0; j < 4; ++j) a0[4 + j] = (ok0 && ms[j] >= PDROP) ? f2bf(xs[j] * INV_KEEP) : 0;
      xs = (const float*)&xa1; ms = (const float*)&ma1;
      #pragma unroll
      for (int j = 0; j < 4; ++j) a1[j] = (ok1 && ms[j] >= PDROP) ? f2bf(xs[j] * INV_KEEP) : 0;
      xs = (const float*)&xb1; ms = (const float*)&mb1;
      #pragma unroll
      for (int j = 0; j < 4; ++j) a1[4 + j] = (ok1 && ms[j] >= PDROP) ? f2bf(xs[j] * INV_KEEP) : 0;
    }

    // prefetch A for step kt+1 (in flight under the MFMAs)
    if (kt + 1 < NT) {
      int o = (kt + 1) * 32;
      xa0 = *(const float4*)(xp0 + o);  xb0 = *(const float4*)(xp0 + o + 4);
      ma0 = *(const float4*)(mp0 + o);  mb0 = *(const float4*)(mp0 + o + 4);
      xa1 = *(const float4*)(xp1 + o);  xb1 = *(const float4*)(xp1 + o + 4);
      ma1 = *(const float4*)(mp1 + o);  mb1 = *(const float4*)(mp1 + o + 4);
    }

    #pragma unroll
    for (int n = 0; n < 8; ++n) {
      acc[0][n] = __builtin_amdgcn_mfma_f32_16x16x32_bf16((short8)a0, b[n], acc[0][n], 0, 0, 0);
      acc[1][n] = __builtin_amdgcn_mfma_f32_16x16x32_bf16((short8)a1, b[n], acc[1][n], 0, 0, 0);
    }
  }

  // epilogue: C/D layout col=lane&15, row=(lane>>4)*4+j; scale by dinv[row]
  int c0 = wn * 128 + fr;
  #pragma unroll
  for (int m = 0; m < 2; ++m) {
    int grb = mb + m * 16 + kg * 4;
    #pragma unroll
    for (int j = 0; j < 4; ++j) {
      int gr = grb + j;
      if (gr < NND) {
        float dv = dinv[gr];
        size_t ro = (size_t)gr * ND + c0;
        #pragma unroll
        for (int n = 0; n < 8; ++n)
          hp[ro + n * 16] = f2bf(acc[m][n][j] * dv);
      }
    }
  }
}

// ---------- gather-aggregate: one wave per node ----------
__global__ void k_aggregate(const unsigned int* __restrict__ lends,   // local ends
                            const unsigned int* __restrict__ bsum,
                            const unsigned int* __restrict__ deg,
                            const int* __restrict__ srcs,
                            const unsigned short* __restrict__ hp,
                            const float* __restrict__ dinv,
                            const float* __restrict__ b,
                            float* __restrict__ out) {
  int node = blockIdx.x * 4 + (threadIdx.x >> 6);
  if (node >= NND) return;
  int lane = threadIdx.x & 63;
  int q = lane * 8;

  float acc[8];
  ushort8 hs = *(const ushort8*)(hp + (size_t)node * ND + q);   // self-loop
  #pragma unroll
  for (int j = 0; j < 8; ++j) acc[j] = bf2f(hs[j]);

  unsigned int d = deg[node];
  unsigned int end = lends[node] + bsum[node >> 8];
  unsigned int beg = end - d;
  for (unsigned int e = beg; e < end; ++e) {
    int s = srcs[e];
    ushort8 hv = *(const ushort8*)(hp + (size_t)s * ND + q);
    #pragma unroll
    for (int j = 0; j < 8; ++j) acc[j] += bf2f(hv[j]);
  }

  float dv = dinv[node];
  float4 b0 = *(const float4*)(b + q);
  float4 b1 = *(const float4*)(b + q + 4);
  float4 o0, o1;
  o0.x = acc[0] * dv + b0.x; o0.y = acc[1] * dv + b0.y;
  o0.z = acc[2] * dv + b0.z; o0.w = acc[3] * dv + b0.w;
  o1.x = acc[4] * dv + b1.x; o1.y = acc[5] * dv + b1.y;
  o1.z = acc[6] * dv + b1.z; o1.w = acc[7] * dv + b1.w;
  float* op = out + (size_t)node * ND + q;
  *(float4*)op = o0;
  *(float4*)(op + 4) = o1;
}

extern "C" void kernel_launch(void* const* d_in, const int* in_sizes, int n_in,
                              void* d_out, int out_size, void* d_ws, size_t ws_size,
                              hipStream_t stream) {
  const float* x  = (const float*)d_in[0];
  const int*   ei = (const int*)d_in[1];     // int64 in reference -> int32 in harness
  const float* W  = (const float*)d_in[2];
  const float* b  = (const float*)d_in[3];
  const float* dm = (const float*)d_in[4];
  float* out = (float*)d_out;

  char* ws = (char*)d_ws;
  unsigned short* wts  = (unsigned short*)(ws + WT_OFF);
  unsigned short* hp   = (unsigned short*)(ws + HP_OFF);
  unsigned int*   deg  = (unsigned int*)(ws + DEG_OFF);
  float*          dinv = (float*)(ws + DINV_OFF);
  unsigned int*   offs = (unsigned int*)(ws + OFFS_OFF);
  int*            srcs = (int*)(ws + SRCS_OFF);
  unsigned int*   bsum = (unsigned int*)(ws + BSUM_OFF);

  hipMemsetAsync(deg, 0, NND * sizeof(unsigned int), stream);
  hipLaunchKernelGGL(k_prep,      dim3(2587),  dim3(256), 0, stream, W, wts, ei, deg);
  hipLaunchKernelGGL(k_scan1,     dim3(391),   dim3(256), 0, stream, deg, offs, bsum, dinv);
  hipLaunchKernelGGL(k_scan2,     dim3(1),     dim3(512), 0, stream, bsum);
  hipLaunchKernelGGL(k_fill,      dim3(1563),  dim3(256), 0, stream, ei, offs, bsum, srcs);
  hipLaunchKernelGGL(k_fused,     dim3(NBLK),  dim3(256), 0, stream, x, dm, wts, dinv, hp);
  hipLaunchKernelGGL(k_aggregate, dim3(25000), dim3(256), 0, stream, offs, bsum, deg, srcs, hp, dinv, b, out);
}

// Round 11
// 318.838 us; speedup vs baseline: 1.3604x; 1.3604x over previous
//
#include <hip/hip_runtime.h>
#include <hip/hip_bf16.h>
#include <stdint.h>

// Problem constants
#define NND   100000      // nodes
#define NED   400000      // edges
#define KD    512         // DIN
#define ND    512         // DOUT
#define PDROP 0.1f
#define INV_KEEP (1.0f/0.9f)

#define BM   64           // rows per block
#define BN   256          // cols per block (2 N-tiles; twin blocks share A via L2/L3)
#define BKF  32           // K per step
#define NT   16           // 512/32 K-steps
#define NMT  1564         // 100096/64 M-tiles
#define NBLK 3128         // NMT * 2

typedef __attribute__((ext_vector_type(4))) float f32x4;
typedef __attribute__((ext_vector_type(8))) short short8;
typedef __attribute__((ext_vector_type(8))) unsigned short ushort8;

// ---- ws layout (bytes) ----
#define WT_OFF   102498304    // wts bf16, chunk-permuted W^T, 512 KB
#define HP_OFF   103022592    // hp_bf16 [MPAD][512]
#define DEG_OFF  205520896    // deg_u32 [NND]
#define DINV_OFF 205920896    // dinv_f32[NND]
#define OFFS_OFF 206320896    // offs_u32[NND] (CSR cursor -> local ends)
#define SRCS_OFF 206720896    // srcs_i32[NED]
#define BSUM_OFF 208320896    // block sums (391 u32)

#define SBAR()   __builtin_amdgcn_sched_barrier(0)
#define WAITV(N) asm volatile("s_waitcnt vmcnt(" #N ")" ::: "memory")
#define WAITL()  asm volatile("s_waitcnt lgkmcnt(0)" ::: "memory")

__device__ __forceinline__ unsigned short f2bf(float f) {
  unsigned int x = __float_as_uint(f);
  unsigned int r = (x + 0x7fffu + ((x >> 16) & 1u)) >> 16;
  return (unsigned short)r;
}
__device__ __forceinline__ float bf2f(unsigned short u) {
  return __uint_as_float(((unsigned int)u) << 16);
}
__device__ __forceinline__ void gload_lds16(const void* g, void* l) {
  __builtin_amdgcn_global_load_lds(
      (const __attribute__((address_space(1))) unsigned int*)g,
      (__attribute__((address_space(3))) unsigned int*)l,
      16, 0, 0);
}
// conflict-free chunk index for 16B chunk (row, g): 16 lanes/frag spread over all banks 2-way
__device__ __forceinline__ int cfc(int row, int g) {
  return row * 4 + ((g + ((row >> 1) & 3)) & 3);
}

// ---------- prep: chunk-permuted W^T to bf16 (blocks 0..1023) + degree count ----------
// wts[idx]: idx = kt*16384 + c*8 + e ; chunk c holds (row = c>>2, g = ((c&3)-((row>>1)&3))&3)
// value = W[kt*32 + g*8 + e][row].  Note (nt*256 + r')-locality: rows nt*256..+255 are
// the contiguous 8192-elem half [kt*16384 + nt*8192, +8192), and local perm == cfc(r',g).
__global__ void k_prep(const float* __restrict__ W, unsigned short* __restrict__ wts,
                       const int* __restrict__ ei, unsigned int* __restrict__ deg) {
  int bb = blockIdx.x;
  if (bb < 1024) {
    int idx = bb * 256 + threadIdx.x;        // 262144 total
    int kt = idx >> 14;
    int c  = (idx >> 3) & 2047;
    int e  = idx & 7;
    int row = c >> 2;
    int g = ((c & 3) - ((row >> 1) & 3)) & 3;
    int k = kt * 32 + g * 8 + e;
    wts[idx] = f2bf(W[(size_t)k * 512 + row]);
  } else {
    int e = (bb - 1024) * 256 + threadIdx.x;
    if (e < NED) atomicAdd(&deg[ei[NED + e]], 1u);   // col = destination
  }
}

// ---------- exclusive scan of deg -> offs (+ dinv fused) ----------
__global__ void k_scan1(const unsigned int* __restrict__ deg,
                        unsigned int* __restrict__ offs, unsigned int* __restrict__ bsum,
                        float* __restrict__ dinv) {
  __shared__ unsigned int s[256];
  int tid = threadIdx.x;
  int i = blockIdx.x * 256 + tid;
  unsigned int v = (i < NND) ? deg[i] : 0u;
  if (i < NND) dinv[i] = rsqrtf((float)(v + 1u));   // +1 self-loop
  s[tid] = v;
  __syncthreads();
  for (int d = 1; d < 256; d <<= 1) {
    unsigned int t = (tid >= d) ? s[tid - d] : 0u;
    __syncthreads();
    s[tid] += t;
    __syncthreads();
  }
  if (i < NND) offs[i] = s[tid] - v;          // block-local exclusive
  if (tid == 255) bsum[blockIdx.x] = s[255];
}
__global__ void k_scan2(unsigned int* __restrict__ bsum) {   // 391 entries
  __shared__ unsigned int s[512];
  int t = threadIdx.x;
  unsigned int v = (t < 391) ? bsum[t] : 0u;
  s[t] = v;
  __syncthreads();
  for (int d = 1; d < 512; d <<= 1) {
    unsigned int u = (t >= d) ? s[t - d] : 0u;
    __syncthreads();
    s[t] += u;
    __syncthreads();
  }
  if (t < 391) bsum[t] = s[t] - v;            // exclusive block offsets
}

// ---------- CSR fill (global pos = local cursor + bsum[dst block]) ----------
__global__ void k_fill(const int* __restrict__ ei, unsigned int* __restrict__ offs,
                       const unsigned int* __restrict__ bsum, int* __restrict__ srcs) {
  int e = blockIdx.x * 256 + threadIdx.x;
  if (e < NED) {
    int dst = ei[NED + e];
    unsigned int pos = atomicAdd(&offs[dst], 1u) + bsum[dst >> 8];
    srcs[pos] = ei[e];
  }
}

// ---------- fused dropout + bf16 MFMA GEMM: hp = dinv_row * (dropout(x) @ W) ----------
// BM=64 x BN=256, BK=32, 512 thr = 8 waves (2M x 4N), wave tile 32x64, acc[2][4].
// LDS 40 KB (As 2x4KB + Bs 2x16KB) -> 4 blocks/CU = 32 waves/CU: four independent
// barrier groups per CU smooth the HBM request stream (R7-R9 plateau diagnosis).
// XCD-chunked swizzle puts the two N-twins of an M-tile on the same XCD -> A-panel
// read twice but second hit L2/L3. Single barrier per K-step, counted vmcnt.
__global__ void __launch_bounds__(512, 4)
k_fused(const float* __restrict__ x, const float* __restrict__ dm,
        const unsigned short* __restrict__ wts,
        const float* __restrict__ dinv,
        unsigned short* __restrict__ hp) {
  __shared__ unsigned short As[2 * 2048];    // 2 x 4 KB, chunked
  __shared__ unsigned short Bs[2 * 8192];    // 2 x 16 KB, chunked

  const int bid = blockIdx.x;
  const int wg = (bid & 7) * (NBLK / 8) + (bid >> 3);   // XCD-chunked bijective
  const int mt = wg >> 1, nt = wg & 1;                  // N-twins adjacent -> same XCD
  const int t = threadIdx.x, wave = t >> 6, lane = t & 63;
  const int wm = wave >> 2, wn = wave & 3;
  const int mb = mt * BM, nb = nt * BN;

  // A staging: thread t -> row t>>3 (0..63), 4 f32 at col (t&7)*4
  const int ar = t >> 3, ag = (t & 7) >> 1, ah = t & 1;
  const bool arow_ok = (mb + ar) < NND;
  const float* xp = x + (size_t)(arow_ok ? mb + ar : 0) * KD + (t & 7) * 4;
  const float* mp = dm + (size_t)(arow_ok ? mb + ar : 0) * KD + (t & 7) * 4;
  const int awoff = cfc(ar, ag) * 16 + ah * 8;   // byte offset within an As half

  const int fr = lane & 15, kg = lane >> 4;
  const int aoff0 = cfc(wm * 32 + fr, kg) * 16;
  const int aoff1 = cfc(wm * 32 + 16 + fr, kg) * 16;

  f32x4 zero = {0.f, 0.f, 0.f, 0.f};
  f32x4 acc[2][4];
  #pragma unroll
  for (int n = 0; n < 4; ++n) { acc[0][n] = zero; acc[1][n] = zero; }

  // ---- prologue ----
  float4 xv0 = *(const float4*)xp;            // Aregs(0)
  float4 mv0 = *(const float4*)mp;
  {  // As[0] (auto-wait drains only the 2 tile-0 loads)
    ushort4 u;
    const float* xs = (const float*)&xv0; const float* ms = (const float*)&mv0;
    #pragma unroll
    for (int j = 0; j < 4; ++j)
      u[j] = (arow_ok && ms[j] >= PDROP) ? f2bf(xs[j] * INV_KEEP) : 0;
    *(ushort4*)((char*)As + awoff) = u;
  }
  #pragma unroll
  for (int i = 0; i < 2; ++i)                 // B(0) -> Bs[0]
    gload_lds16(wts + (size_t)nt * 8192 + (size_t)(i * 512 + t) * 8,
                (char*)Bs + (i * 512 + t) * 16);
  float4 xvA = *(const float4*)(xp + BKF);    // Aregs(1)
  float4 mvA = *(const float4*)(mp + BKF);
  float4 xvB = *(const float4*)(xp + 2 * BKF);  // Aregs(2)
  float4 mvB = *(const float4*)(mp + 2 * BKF);

  // ---- main loop: ONE barrier per K-step ----
  for (int kt = 0; kt < NT; ++kt) {
    const int cur = kt & 1;

    SBAR();
    if (kt == 0)           { WAITV(4); }   // B(0) arrived; xvA,xvB in flight
    else if (kt < NT - 2)  { WAITV(2); }   // B(kt) arrived; Aregs(kt+2) in flight
    else                   { WAITV(0); }   // tail
    WAITL();                               // own ds_write A(kt) drained
    SBAR();
    __builtin_amdgcn_s_barrier();          // buf[cur] fully staged, buf[cur^1] free
    SBAR();

    if (kt + 1 < NT) {
      {  // ds_write A(kt+1) from xvA (loaded 2 iters ago; auto-wait satisfied)
        ushort4 u;
        const float* xs = (const float*)&xvA; const float* ms = (const float*)&mvA;
        #pragma unroll
        for (int j = 0; j < 4; ++j)
          u[j] = (arow_ok && ms[j] >= PDROP) ? f2bf(xs[j] * INV_KEEP) : 0;
        *(ushort4*)((char*)As + (cur ^ 1) * 4096 + awoff) = u;
      }
      {  // gload B(kt+1) -> Bs[cur^1]  (issued AFTER ds_write)
        const unsigned short* src = wts + (size_t)(kt + 1) * 16384 + (size_t)nt * 8192;
        char* dst = (char*)Bs + (cur ^ 1) * 16384;
        #pragma unroll
        for (int i = 0; i < 2; ++i)
          gload_lds16(src + (size_t)(i * 512 + t) * 8, dst + (i * 512 + t) * 16);
      }
      xvA = xvB; mvA = mvB;                // shift pipeline
      if (kt + 3 < NT) {                   // load Aregs(kt+3)
        xvB = *(const float4*)(xp + (kt + 3) * BKF);
        mvB = *(const float4*)(mp + (kt + 3) * BKF);
      }
    }
    SBAR();

    // compute(kt) from buf[cur]
    const char* ab = (const char*)As + cur * 4096;
    const char* bb = (const char*)Bs + cur * 16384;
    short8 a0 = *(const short8*)(ab + aoff0);
    short8 a1 = *(const short8*)(ab + aoff1);
    #pragma unroll
    for (int n = 0; n < 4; ++n) {
      short8 b = *(const short8*)(bb + cfc(wn * 64 + n * 16 + fr, kg) * 16);
      acc[0][n] = __builtin_amdgcn_mfma_f32_16x16x32_bf16(a0, b, acc[0][n], 0, 0, 0);
      acc[1][n] = __builtin_amdgcn_mfma_f32_16x16x32_bf16(a1, b, acc[1][n], 0, 0, 0);
    }
  }

  // epilogue: C/D layout col=lane&15, row=(lane>>4)*4+j; scale by dinv[row]
  int c0 = nb + wn * 64 + fr;
  #pragma unroll
  for (int m = 0; m < 2; ++m) {
    int grb = mb + wm * 32 + m * 16 + kg * 4;
    #pragma unroll
    for (int j = 0; j < 4; ++j) {
      int gr = grb + j;
      if (gr < NND) {
        float dv = dinv[gr];
        size_t ro = (size_t)gr * ND + c0;
        #pragma unroll
        for (int n = 0; n < 4; ++n)
          hp[ro + n * 16] = f2bf(acc[m][n][j] * dv);
      }
    }
  }
}

// ---------- gather-aggregate: one wave per node ----------
__global__ void k_aggregate(const unsigned int* __restrict__ lends,   // local ends
                            const unsigned int* __restrict__ bsum,
                            const unsigned int* __restrict__ deg,
                            const int* __restrict__ srcs,
                            const unsigned short* __restrict__ hp,
                            const float* __restrict__ dinv,
                            const float* __restrict__ b,
                            float* __restrict__ out) {
  int node = blockIdx.x * 4 + (threadIdx.x >> 6);
  if (node >= NND) return;
  int lane = threadIdx.x & 63;
  int q = lane * 8;

  float acc[8];
  ushort8 hs = *(const ushort8*)(hp + (size_t)node * ND + q);   // self-loop
  #pragma unroll
  for (int j = 0; j < 8; ++j) acc[j] = bf2f(hs[j]);

  unsigned int d = deg[node];
  unsigned int end = lends[node] + bsum[node >> 8];
  unsigned int beg = end - d;
  for (unsigned int e = beg; e < end; ++e) {
    int s = srcs[e];
    ushort8 hv = *(const ushort8*)(hp + (size_t)s * ND + q);
    #pragma unroll
    for (int j = 0; j < 8; ++j) acc[j] += bf2f(hv[j]);
  }

  float dv = dinv[node];
  float4 b0 = *(const float4*)(b + q);
  float4 b1 = *(const float4*)(b + q + 4);
  float4 o0, o1;
  o0.x = acc[0] * dv + b0.x; o0.y = acc[1] * dv + b0.y;
  o0.z = acc[2] * dv + b0.z; o0.w = acc[3] * dv + b0.w;
  o1.x = acc[4] * dv + b1.x; o1.y = acc[5] * dv + b1.y;
  o1.z = acc[6] * dv + b1.z; o1.w = acc[7] * dv + b1.w;
  float* op = out + (size_t)node * ND + q;
  *(float4*)op = o0;
  *(float4*)(op + 4) = o1;
}

extern "C" void kernel_launch(void* const* d_in, const int* in_sizes, int n_in,
                              void* d_out, int out_size, void* d_ws, size_t ws_size,
                              hipStream_t stream) {
  const float* x  = (const float*)d_in[0];
  const int*   ei = (const int*)d_in[1];     // int64 in reference -> int32 in harness
  const float* W  = (const float*)d_in[2];
  const float* b  = (const float*)d_in[3];
  const float* dm = (const float*)d_in[4];
  float* out = (float*)d_out;

  char* ws = (char*)d_ws;
  unsigned short* wts  = (unsigned short*)(ws + WT_OFF);
  unsigned short* hp   = (unsigned short*)(ws + HP_OFF);
  unsigned int*   deg  = (unsigned int*)(ws + DEG_OFF);
  float*          dinv = (float*)(ws + DINV_OFF);
  unsigned int*   offs = (unsigned int*)(ws + OFFS_OFF);
  int*            srcs = (int*)(ws + SRCS_OFF);
  unsigned int*   bsum = (unsigned int*)(ws + BSUM_OFF);

  hipMemsetAsync(deg, 0, NND * sizeof(unsigned int), stream);
  hipLaunchKernelGGL(k_prep,      dim3(2587),  dim3(256), 0, stream, W, wts, ei, deg);
  hipLaunchKernelGGL(k_scan1,     dim3(391),   dim3(256), 0, stream, deg, offs, bsum, dinv);
  hipLaunchKernelGGL(k_scan2,     dim3(1),     dim3(512), 0, stream, bsum);
  hipLaunchKernelGGL(k_fill,      dim3(1563),  dim3(256), 0, stream, ei, offs, bsum, srcs);
  hipLaunchKernelGGL(k_fused,     dim3(NBLK),  dim3(512), 0, stream, x, dm, wts, dinv, hp);
  hipLaunchKernelGGL(k_aggregate, dim3(25000), dim3(256), 0, stream, offs, bsum, deg, srcs, hp, dinv, b, out);
}